// Round 4
// baseline (684.613 us; speedup 1.0000x reference)
//
#include <hip/hip_runtime.h>
#include <stdint.h>

typedef unsigned short u16;
typedef uint32_t u32;
typedef __attribute__((ext_vector_type(4))) float f32x4;
typedef __attribute__((ext_vector_type(8))) short bf16x8;

#define DEVINL __device__ __forceinline__

DEVINL u16 f2bf(float f) {
    union { float f; u32 u; } a; a.f = f;
    u32 u = a.u;
    return (u16)((u + 0x7fffu + ((u >> 16) & 1u)) >> 16);   // RNE
}
DEVINL u32 pk2(float a, float b) { return (u32)f2bf(a) | ((u32)f2bf(b) << 16); }

// 128B-row swizzled tile (conflict-free vector row reads) — R2-verified
DEVINL u32 swz128(u32 row, u32 colb) { return row * 128u + (colb ^ ((row & 7u) << 4)); }

// async global->LDS, 16B per lane
DEVINL void gload_lds16(const u16* g, char* l) {
    __builtin_amdgcn_global_load_lds(
        (const __attribute__((address_space(1))) void*)g,
        (__attribute__((address_space(3))) void*)l, 16, 0, 0);
}

// 4x4 transpose among 4 lanes (lane&3) over the 4 regs of v:
// result: (lane q, reg r) holds original (lane r, reg q).  2-stage butterfly.
DEVINL f32x4 trans4(f32x4 v, int q) {
    float s0 = __shfl_xor(v[0], 1), s1 = __shfl_xor(v[1], 1),
          s2 = __shfl_xor(v[2], 1), s3 = __shfl_xor(v[3], 1);
    f32x4 t;
    bool q1 = (q & 1) != 0;
    t[0] = q1 ? s1 : v[0];
    t[1] = q1 ? v[1] : s0;
    t[2] = q1 ? s3 : v[2];
    t[3] = q1 ? v[3] : s2;
    float u0 = __shfl_xor(t[0], 2), u1 = __shfl_xor(t[1], 2),
          u2 = __shfl_xor(t[2], 2), u3 = __shfl_xor(t[3], 2);
    f32x4 r;
    bool q2 = (q & 2) != 0;
    r[0] = q2 ? u2 : t[0];
    r[1] = q2 ? u3 : t[1];
    r[2] = q2 ? t[2] : u0;
    r[3] = q2 ? t[3] : u1;
    return r;
}

// ---------------------------------------------------------------------------
// Kernel 0: fp32 -> bf16 convert pass
// ---------------------------------------------------------------------------
__global__ __launch_bounds__(256) void convert_kernel(
    const float* __restrict__ x, const float* __restrict__ Wq,
    const float* __restrict__ Wk, const float* __restrict__ Wv,
    const float* __restrict__ Wo, const float* __restrict__ Wlr,
    const float* __restrict__ Wbeta,
    u16* __restrict__ xb, u16* __restrict__ wb, u16* __restrict__ wob,
    u16* __restrict__ wlb)
{
    const int t0 = blockIdx.x * 256 + threadIdx.x;
    const int stride = gridDim.x * 256;
    auto cv = [&](const float* src, u16* dst, int n4) {
        for (int i = t0; i < n4; i += stride) {
            float4 v = ((const float4*)src)[i];
            uint2 p;
            p.x = pk2(v.x, v.y);
            p.y = pk2(v.z, v.w);
            ((uint2*)dst)[i] = p;
        }
    };
    cv(x, xb, 4194304);
    cv(Wq, wb, 262144);
    cv(Wk, wb + 1048576, 262144);
    cv(Wv, wb + 2097152, 262144);
    cv(Wo, wob, 262144);
    cv(Wlr, wlb, 8192);
    cv(Wbeta, wlb + 32768, 8192);
}

// ---------------------------------------------------------------------------
// Kernel A: q/k/v projections (bf16 in, bf16 out, fused silu for q,k)
// ---------------------------------------------------------------------------
__global__ __launch_bounds__(256) void proj_qkv_kernel(
    const u16* __restrict__ xb, const u16* __restrict__ wb,
    u16* __restrict__ qb, u16* __restrict__ kb, u16* __restrict__ vb)
{
    __shared__ __align__(16) char As[128 * 128];
    __shared__ __align__(16) char Bs[128 * 128];
    const int bn = blockIdx.x;
    const int bm = blockIdx.y;
    const int wsel = bn >> 3;
    u16* __restrict__ dst = (wsel == 0) ? qb : ((wsel == 1) ? kb : vb);
    const int cb = (bn & 7) * 128;
    const int wrow = bn * 128;
    const int rb = bm * 128;
    const int tid = threadIdx.x;
    const int lane = tid & 63;
    const int wv = tid >> 6;
    const int wr = (wv >> 1) * 64, wc = (wv & 1) * 64;
    const int li = lane & 15, g = lane >> 4;
    const int lr8 = lane >> 3, lc8 = lane & 7;

    f32x4 acc[4][4];
#pragma unroll
    for (int i = 0; i < 4; ++i)
#pragma unroll
        for (int j = 0; j < 4; ++j) acc[i][j] = (f32x4)0.0f;

    for (int k0 = 0; k0 < 1024; k0 += 64) {
        __syncthreads();
#pragma unroll
        for (int ld = 0; ld < 4; ++ld) {
            int r0 = wv * 32 + ld * 8;
            gload_lds16(xb + (size_t)(rb + r0 + lr8) * 1024 + k0 + lc8 * 8, As + r0 * 128);
            gload_lds16(wb + (size_t)(wrow + r0 + lr8) * 1024 + k0 + lc8 * 8, Bs + r0 * 128);
        }
        __syncthreads();
#pragma unroll
        for (int ks = 0; ks < 2; ++ks) {
            bf16x8 af[4], bfr[4];
#pragma unroll
            for (int m = 0; m < 4; ++m)
                af[m] = *(const bf16x8*)(As + (wr + m * 16 + li) * 128 + ks * 64 + g * 16);
#pragma unroll
            for (int n = 0; n < 4; ++n)
                bfr[n] = *(const bf16x8*)(Bs + (wc + n * 16 + li) * 128 + ks * 64 + g * 16);
#pragma unroll
            for (int m = 0; m < 4; ++m)
#pragma unroll
                for (int n = 0; n < 4; ++n)
                    acc[m][n] = __builtin_amdgcn_mfma_f32_16x16x32_bf16(af[m], bfr[n], acc[m][n], 0, 0, 0);
        }
    }
    const bool do_silu = (wsel < 2);
#pragma unroll
    for (int m = 0; m < 4; ++m) {
        int t = rb + wr + m * 16 + g * 4;
#pragma unroll
        for (int r = 0; r < 4; ++r) {
#pragma unroll
            for (int n = 0; n < 4; ++n) {
                float v = acc[m][n][r];
                if (do_silu) v = v / (1.0f + __expf(-v));
                int col = cb + wc + n * 16 + li;
                dst[(size_t)(t + r) * 1024 + col] = f2bf(v);
            }
        }
    }
}

// ---------------------------------------------------------------------------
// Kernel B: lr/wd heads as MFMA GEMM + on-chip per-chunk mean
// ---------------------------------------------------------------------------
__global__ __launch_bounds__(256) void lrwd_kernel(
    const u16* __restrict__ xb, const u16* __restrict__ wlb,
    float* __restrict__ lrc_all)
{
    __shared__ __align__(16) char As[128 * 128];
    __shared__ __align__(16) char Bs[64 * 128];
    __shared__ float red[128][65];
    const int bm = blockIdx.x;
    const int rb = bm * 128;
    const int tid = threadIdx.x;
    const int lane = tid & 63;
    const int wv = tid >> 6;
    const int li = lane & 15, g = lane >> 4;
    const int lr8 = lane >> 3, lc8 = lane & 7;

    f32x4 acc[2][4];
#pragma unroll
    for (int i = 0; i < 2; ++i)
#pragma unroll
        for (int j = 0; j < 4; ++j) acc[i][j] = (f32x4)0.0f;

    for (int k0 = 0; k0 < 1024; k0 += 64) {
        __syncthreads();
#pragma unroll
        for (int ld = 0; ld < 4; ++ld) {
            int r0 = wv * 32 + ld * 8;
            gload_lds16(xb + (size_t)(rb + r0 + lr8) * 1024 + k0 + lc8 * 8, As + r0 * 128);
        }
#pragma unroll
        for (int ld = 0; ld < 2; ++ld) {
            int r0 = wv * 16 + ld * 8;
            gload_lds16(wlb + (size_t)(r0 + lr8) * 1024 + k0 + lc8 * 8, Bs + r0 * 128);
        }
        __syncthreads();
#pragma unroll
        for (int ks = 0; ks < 2; ++ks) {
            bf16x8 af[2], bfr[4];
#pragma unroll
            for (int m = 0; m < 2; ++m)
                af[m] = *(const bf16x8*)(As + (wv * 32 + m * 16 + li) * 128 + ks * 64 + g * 16);
#pragma unroll
            for (int n = 0; n < 4; ++n)
                bfr[n] = *(const bf16x8*)(Bs + (n * 16 + li) * 128 + ks * 64 + g * 16);
#pragma unroll
            for (int m = 0; m < 2; ++m)
#pragma unroll
                for (int n = 0; n < 4; ++n)
                    acc[m][n] = __builtin_amdgcn_mfma_f32_16x16x32_bf16(af[m], bfr[n], acc[m][n], 0, 0, 0);
        }
    }
#pragma unroll
    for (int m = 0; m < 2; ++m) {
#pragma unroll
        for (int n = 0; n < 4; ++n) {
            int col = n * 16 + li;
            float scale = (col < 32) ? 1e-3f : 0.9f;
#pragma unroll
            for (int r = 0; r < 4; ++r) {
                int t = wv * 32 + m * 16 + g * 4 + r;
                float s = acc[m][n][r];
                red[t][col] = scale / (1.0f + __expf(-s));
            }
        }
    }
    __syncthreads();
    if (tid < 128) {
        int chunk = tid >> 6, col = tid & 63;
        float s = 0.f;
#pragma unroll
        for (int i = 0; i < 64; ++i) s += red[chunk * 64 + i][col];
        int b = bm >> 5;
        int cidx = (bm & 31) * 2 + chunk;
        lrc_all[((size_t)(b * 64 + cidx)) * 64 + col] = s * (1.0f / 64.0f);
    }
}

// ---------------------------------------------------------------------------
// Kernel C: chunk scan.  One block per (b,h); 4 waves; fp32 state in regs;
// all LDS tiles [row][k-contig] swz128; transposed operands produced via
// register 4x4 transposes (lane-local for K/V commit, 4-lane shfl for P/gz/W).
// All MFMA fragment mappings identical to the R2-verified kernel.
// ---------------------------------------------------------------------------
__global__ __launch_bounds__(256) void scan_kernel(
    const u16* __restrict__ qb, const u16* __restrict__ kb, const u16* __restrict__ vb,
    const float* __restrict__ lrc_all, const float* __restrict__ Wi0,
    const float* __restrict__ Wo0, u16* __restrict__ ob)
{
    const int bh = blockIdx.x;
    const int b = bh >> 4, h = bh & 15;
    const int tid = threadIdx.x;
    const int lane = tid & 63;
    const int w = tid >> 6;
    const int li = lane & 15, g = lane >> 4;
    const int q4 = li & 3, b4 = li & 12;   // transpose-write lane split

    __shared__ __align__(16) char SWiN[8192];   // Wi  [D][d]
    __shared__ __align__(16) char SWoN[8192];   // Wo  [D][d]
    __shared__ __align__(16) char SWoT[8192];   // Wo^T[d][D]
    __shared__ __align__(16) char SQ[8192];     // q   [n][d]
    __shared__ __align__(16) char Kc[8192];     // k   [n][d]
    __shared__ __align__(16) char Vc[8192];     // v   [n][d]
    __shared__ __align__(16) char KcT[8192];    // k^T [d][n]
    __shared__ __align__(16) char VcT[8192];    // v^T [d][n]
    __shared__ __align__(16) char SPQ[8192];    // pq  [n][D]
    __shared__ __align__(16) char SPTN[8192];   // p^T [D][n]
    __shared__ __align__(16) char SGZN[8192];   // gz^T[D][n]
    __shared__ float spart[256];
    __shared__ float lrc[256];

    // ---- state init: fp32 regs in MFMA C-layout + LDS mirrors ----
    f32x4 WiR[4], WoR[4];
#pragma unroll
    for (int tn = 0; tn < 4; ++tn) {
        int d = tn * 16 + li;
#pragma unroll
        for (int r = 0; r < 4; ++r) {
            int D = w * 16 + g * 4 + r;
            WiR[tn][r] = Wi0[((size_t)D * 16 + h) * 64 + d];
            WoR[tn][r] = Wo0[((size_t)D * 16 + h) * 64 + d];
        }
        // SWoT[d][D] direct from C-layout
        *(uint2*)(SWoT + swz128(d, w * 32 + g * 8)) =
            make_uint2(pk2(WoR[tn][0], WoR[tn][1]), pk2(WoR[tn][2], WoR[tn][3]));
        // SWiN/SWoN rows via direct (transposed-ownership) global reads
        int Dn = w * 16 + g * 4 + q4;
        int dn = tn * 16 + b4;
        float4 fi = *(const float4*)(Wi0 + ((size_t)Dn * 16 + h) * 64 + dn);
        float4 fo = *(const float4*)(Wo0 + ((size_t)Dn * 16 + h) * 64 + dn);
        *(uint2*)(SWiN + swz128(Dn, tn * 32 + b4 * 2)) =
            make_uint2(pk2(fi.x, fi.y), pk2(fi.z, fi.w));
        *(uint2*)(SWoN + swz128(Dn, tn * 32 + b4 * 2)) =
            make_uint2(pk2(fo.x, fo.y), pk2(fo.z, fo.w));
    }
    {
        int cc = tid >> 2, j = tid & 3;
        lrc[cc * 4 + j] = lrc_all[((size_t)(b * 64 + cc)) * 64 + j * 16 + h];
    }

    const int nb4 = (tid >> 4) * 4;   // K/V block row base (0..60)
    const int db4 = (tid & 15) * 4;   // K/V block col base (0..60)
    uint4 pq_[2];
    uint2 pk_[4], pv_[4];
    auto prefetch = [&](int c) {
        const size_t base = ((size_t)(b * 4096 + c * 64)) * 1024 + h * 64;
#pragma unroll
        for (int p = 0; p < 2; ++p) {
            int id = p * 256 + tid;
            int n = id >> 3;
            int d0 = (id & 7) * 8;
            pq_[p] = *(const uint4*)(qb + base + (size_t)n * 1024 + d0);
        }
#pragma unroll
        for (int j = 0; j < 4; ++j) {
            pk_[j] = *(const uint2*)(kb + base + (size_t)(nb4 + j) * 1024 + db4);
            pv_[j] = *(const uint2*)(vb + base + (size_t)(nb4 + j) * 1024 + db4);
        }
    };
    auto commit = [&]() {
#pragma unroll
        for (int p = 0; p < 2; ++p) {
            int id = p * 256 + tid;
            int n = id >> 3;
            int d0 = (id & 7) * 8;
            *(uint4*)(SQ + swz128(n, d0 * 2)) = pq_[p];
        }
#pragma unroll
        for (int j = 0; j < 4; ++j) {
            *(uint2*)(Kc + swz128(nb4 + j, db4 * 2)) = pk_[j];
            *(uint2*)(Vc + swz128(nb4 + j, db4 * 2)) = pv_[j];
        }
        // lane-local 4x4 bf16 transpose of the K/V blocks -> [d][n] tiles
#pragma unroll
        for (int i = 0; i < 4; ++i) {
            u32 k0 = (((i & 2) ? pk_[0].y : pk_[0].x) >> ((i & 1) * 16)) & 0xffffu;
            u32 k1 = (((i & 2) ? pk_[1].y : pk_[1].x) >> ((i & 1) * 16)) & 0xffffu;
            u32 k2 = (((i & 2) ? pk_[2].y : pk_[2].x) >> ((i & 1) * 16)) & 0xffffu;
            u32 k3 = (((i & 2) ? pk_[3].y : pk_[3].x) >> ((i & 1) * 16)) & 0xffffu;
            *(uint2*)(KcT + swz128(db4 + i, nb4 * 2)) =
                make_uint2(k0 | (k1 << 16), k2 | (k3 << 16));
            u32 v0 = (((i & 2) ? pv_[0].y : pv_[0].x) >> ((i & 1) * 16)) & 0xffffu;
            u32 v1 = (((i & 2) ? pv_[1].y : pv_[1].x) >> ((i & 1) * 16)) & 0xffffu;
            u32 v2 = (((i & 2) ? pv_[2].y : pv_[2].x) >> ((i & 1) * 16)) & 0xffffu;
            u32 v3 = (((i & 2) ? pv_[3].y : pv_[3].x) >> ((i & 1) * 16)) & 0xffffu;
            *(uint2*)(VcT + swz128(db4 + i, nb4 * 2)) =
                make_uint2(v0 | (v1 << 16), v2 | (v3 << 16));
        }
    };

    prefetch(0);
    commit();
    __syncthreads();

    for (int c = 0; c < 64; ++c) {
        if (c + 1 < 64) prefetch(c + 1);

        // ---- Wi A-fragments (shared by M1, M2) ----
        bf16x8 wiA0 = *(const bf16x8*)(SWiN + swz128(w * 16 + li, g * 16));
        bf16x8 wiA1 = *(const bf16x8*)(SWiN + swz128(w * 16 + li, 64 + g * 16));

        // ---- M1: Sq^T[D][n] = Wi . q^T ; softmax over n ; -> SPQ[n][D] ----
        f32x4 sq[4];
#pragma unroll
        for (int tn = 0; tn < 4; ++tn) {
            bf16x8 b0 = *(const bf16x8*)(SQ + swz128(tn * 16 + li, g * 16));
            bf16x8 b1 = *(const bf16x8*)(SQ + swz128(tn * 16 + li, 64 + g * 16));
            f32x4 z = (f32x4)0.0f;
            z = __builtin_amdgcn_mfma_f32_16x16x32_bf16(wiA0, b0, z, 0, 0, 0);
            z = __builtin_amdgcn_mfma_f32_16x16x32_bf16(wiA1, b1, z, 0, 0, 0);
            sq[tn] = z;
        }
#pragma unroll
        for (int r = 0; r < 4; ++r) {
            float m = fmaxf(fmaxf(sq[0][r], sq[1][r]), fmaxf(sq[2][r], sq[3][r]));
            m = fmaxf(m, __shfl_xor(m, 1)); m = fmaxf(m, __shfl_xor(m, 2));
            m = fmaxf(m, __shfl_xor(m, 4)); m = fmaxf(m, __shfl_xor(m, 8));
            float e0 = __expf(sq[0][r] - m), e1 = __expf(sq[1][r] - m);
            float e2 = __expf(sq[2][r] - m), e3 = __expf(sq[3][r] - m);
            float s = e0 + e1 + e2 + e3;
            s += __shfl_xor(s, 1); s += __shfl_xor(s, 2);
            s += __shfl_xor(s, 4); s += __shfl_xor(s, 8);
            float inv = 1.0f / s;
            sq[0][r] = e0 * inv; sq[1][r] = e1 * inv; sq[2][r] = e2 * inv; sq[3][r] = e3 * inv;
        }
#pragma unroll
        for (int tn = 0; tn < 4; ++tn) {
            int n = tn * 16 + li;
            *(uint2*)(SPQ + swz128(n, (w * 16 + g * 4) * 2)) =
                make_uint2(pk2(sq[tn][0], sq[tn][1]), pk2(sq[tn][2], sq[tn][3]));
        }

        // ---- M2: Sk^T -> p^T (regs) ----
        f32x4 pk[4];
#pragma unroll
        for (int tn = 0; tn < 4; ++tn) {
            bf16x8 b0 = *(const bf16x8*)(Kc + swz128(tn * 16 + li, g * 16));
            bf16x8 b1 = *(const bf16x8*)(Kc + swz128(tn * 16 + li, 64 + g * 16));
            f32x4 z = (f32x4)0.0f;
            z = __builtin_amdgcn_mfma_f32_16x16x32_bf16(wiA0, b0, z, 0, 0, 0);
            z = __builtin_amdgcn_mfma_f32_16x16x32_bf16(wiA1, b1, z, 0, 0, 0);
            pk[tn] = z;
        }
#pragma unroll
        for (int r = 0; r < 4; ++r) {
            float m = fmaxf(fmaxf(pk[0][r], pk[1][r]), fmaxf(pk[2][r], pk[3][r]));
            m = fmaxf(m, __shfl_xor(m, 1)); m = fmaxf(m, __shfl_xor(m, 2));
            m = fmaxf(m, __shfl_xor(m, 4)); m = fmaxf(m, __shfl_xor(m, 8));
            float e0 = __expf(pk[0][r] - m), e1 = __expf(pk[1][r] - m);
            float e2 = __expf(pk[2][r] - m), e3 = __expf(pk[3][r] - m);
            float s = e0 + e1 + e2 + e3;
            s += __shfl_xor(s, 1); s += __shfl_xor(s, 2);
            s += __shfl_xor(s, 4); s += __shfl_xor(s, 8);
            float inv = 1.0f / s;
            pk[0][r] = e0 * inv; pk[1][r] = e1 * inv; pk[2][r] = e2 * inv; pk[3][r] = e3 * inv;
        }

        // ---- M4': a^T[D][n] = Wo . v^T ----
        bf16x8 woA0 = *(const bf16x8*)(SWoN + swz128(w * 16 + li, g * 16));
        bf16x8 woA1 = *(const bf16x8*)(SWoN + swz128(w * 16 + li, 64 + g * 16));
        f32x4 aT[4];
#pragma unroll
        for (int tn = 0; tn < 4; ++tn) {
            bf16x8 b0 = *(const bf16x8*)(Vc + swz128(tn * 16 + li, g * 16));
            bf16x8 b1 = *(const bf16x8*)(Vc + swz128(tn * 16 + li, 64 + g * 16));
            f32x4 z = (f32x4)0.0f;
            z = __builtin_amdgcn_mfma_f32_16x16x32_bf16(woA0, b0, z, 0, 0, 0);
            z = __builtin_amdgcn_mfma_f32_16x16x32_bf16(woA1, b1, z, 0, 0, 0);
            aT[tn] = z;
        }
        // s[n] partials over this wave's 16 D-rows
#pragma unroll
        for (int tn = 0; tn < 4; ++tn) {
            f32x4 t4 = pk[tn] * aT[tn];
            float s_ = t4[0] + t4[1] + t4[2] + t4[3];
            s_ += __shfl_xor(s_, 16);
            s_ += __shfl_xor(s_, 32);
            if (g == 0) spart[w * 64 + tn * 16 + li] = s_;
        }
        __syncthreads();   // B: spart, SPQ visible

        // ---- gz^T = p^T (s - a^T) (regs, C-layout) ----
        f32x4 gz[4];
#pragma unroll
        for (int tn = 0; tn < 4; ++tn) {
            int n = tn * 16 + li;
            float sn = spart[n] + spart[64 + n] + spart[128 + n] + spart[192 + n];
#pragma unroll
            for (int r = 0; r < 4; ++r) gz[tn][r] = pk[tn][r] * (sn - aT[tn][r]);
        }

        // ---- M3: o[n][d] = pq . Wo  (A: SPQ rows; B: SWoT rows) ----
        {
            bf16x8 a0 = *(const bf16x8*)(SPQ + swz128(w * 16 + li, g * 16));
            bf16x8 a1 = *(const bf16x8*)(SPQ + swz128(w * 16 + li, 64 + g * 16));
            f32x4 o4[4];
#pragma unroll
            for (int tn = 0; tn < 4; ++tn) {
                bf16x8 b0 = *(const bf16x8*)(SWoT + swz128(tn * 16 + li, g * 16));
                bf16x8 b1 = *(const bf16x8*)(SWoT + swz128(tn * 16 + li, 64 + g * 16));
                f32x4 z = (f32x4)0.0f;
                z = __builtin_amdgcn_mfma_f32_16x16x32_bf16(a0, b0, z, 0, 0, 0);
                z = __builtin_amdgcn_mfma_f32_16x16x32_bf16(a1, b1, z, 0, 0, 0);
                o4[tn] = z;
            }
            const size_t obase = ((size_t)(b * 4096 + c * 64)) * 1024 + h * 64;
#pragma unroll
            for (int tn = 0; tn < 4; ++tn) {
                int d = tn * 16 + li;
#pragma unroll
                for (int r = 0; r < 4; ++r) {
                    int n = w * 16 + g * 4 + r;
                    ob[obase + (size_t)n * 1024 + d] = f2bf(o4[tn][r]);
                }
            }
        }

        // ---- 4-lane register transposes: pk, gz -> [D][n] tiles (own rows) ----
#pragma unroll
        for (int tn = 0; tn < 4; ++tn) {
            f32x4 tp = trans4(pk[tn], q4);
            *(uint2*)(SPTN + swz128(w * 16 + g * 4 + q4, tn * 32 + b4 * 2)) =
                make_uint2(pk2(tp[0], tp[1]), pk2(tp[2], tp[3]));
            f32x4 tg = trans4(gz[tn], q4);
            *(uint2*)(SGZN + swz128(w * 16 + g * 4 + q4, tn * 32 + b4 * 2)) =
                make_uint2(pk2(tg[0], tg[1]), pk2(tg[2], tg[3]));
        }

        // ---- M5: go[D][d] = p^T . v  (A: SPTN rows (own wave); B: VcT rows) ----
        f32x4 go[4];
        {
            bf16x8 a0 = *(const bf16x8*)(SPTN + swz128(w * 16 + li, g * 16));
            bf16x8 a1 = *(const bf16x8*)(SPTN + swz128(w * 16 + li, 64 + g * 16));
#pragma unroll
            for (int tn = 0; tn < 4; ++tn) {
                bf16x8 b0 = *(const bf16x8*)(VcT + swz128(tn * 16 + li, g * 16));
                bf16x8 b1 = *(const bf16x8*)(VcT + swz128(tn * 16 + li, 64 + g * 16));
                f32x4 z = (f32x4)0.0f;
                z = __builtin_amdgcn_mfma_f32_16x16x32_bf16(a0, b0, z, 0, 0, 0);
                z = __builtin_amdgcn_mfma_f32_16x16x32_bf16(a1, b1, z, 0, 0, 0);
                go[tn] = z;
            }
        }
        // ---- M6: gi[D][d] = gz^T . k  (A: SGZN rows; B: KcT rows) ----
        f32x4 gi[4];
        {
            bf16x8 a0 = *(const bf16x8*)(SGZN + swz128(w * 16 + li, g * 16));
            bf16x8 a1 = *(const bf16x8*)(SGZN + swz128(w * 16 + li, 64 + g * 16));
#pragma unroll
            for (int tn = 0; tn < 4; ++tn) {
                bf16x8 b0 = *(const bf16x8*)(KcT + swz128(tn * 16 + li, g * 16));
                bf16x8 b1 = *(const bf16x8*)(KcT + swz128(tn * 16 + li, 64 + g * 16));
                f32x4 z = (f32x4)0.0f;
                z = __builtin_amdgcn_mfma_f32_16x16x32_bf16(a0, b0, z, 0, 0, 0);
                z = __builtin_amdgcn_mfma_f32_16x16x32_bf16(a1, b1, z, 0, 0, 0);
                gi[tn] = z;
            }
        }
        __syncthreads();   // C: all reads of shared tiles complete

        if (c + 1 < 64) {
            float lin = lrc[c * 4 + 0], lout = lrc[c * 4 + 1];
            float win = lrc[c * 4 + 2], wout = lrc[c * 4 + 3];
#pragma unroll
            for (int tn = 0; tn < 4; ++tn) {
                WiR[tn] = win * WiR[tn] - lin * gi[tn];
                WoR[tn] = wout * WoR[tn] + lout * go[tn];   // grad_out = -go
                int d = tn * 16 + li;
                // SWoT[d][D] direct from C-layout
                *(uint2*)(SWoT + swz128(d, w * 32 + g * 8)) =
                    make_uint2(pk2(WoR[tn][0], WoR[tn][1]), pk2(WoR[tn][2], WoR[tn][3]));
                // SWiN/SWoN rows via 4-lane transpose
                f32x4 ti = trans4(WiR[tn], q4);
                *(uint2*)(SWiN + swz128(w * 16 + g * 4 + q4, tn * 32 + b4 * 2)) =
                    make_uint2(pk2(ti[0], ti[1]), pk2(ti[2], ti[3]));
                f32x4 to = trans4(WoR[tn], q4);
                *(uint2*)(SWoN + swz128(w * 16 + g * 4 + q4, tn * 32 + b4 * 2)) =
                    make_uint2(pk2(to[0], to[1]), pk2(to[2], to[3]));
            }
            commit();
        }
        __syncthreads();   // A: next chunk staged + state visible
    }
}

// ---------------------------------------------------------------------------
// Kernel D: out[t][m] = sum_j o[t][j] * Wo[m][j]
// ---------------------------------------------------------------------------
__global__ __launch_bounds__(256) void out_proj_kernel(
    const u16* __restrict__ ob, const u16* __restrict__ wob, float* __restrict__ out)
{
    __shared__ __align__(16) char As[128 * 128];
    __shared__ __align__(16) char Bs[128 * 128];
    const int bn = blockIdx.x;
    const int bm = blockIdx.y;
    const int cb = bn * 128;
    const int rb = bm * 128;
    const int tid = threadIdx.x;
    const int lane = tid & 63;
    const int wv = tid >> 6;
    const int wr = (wv >> 1) * 64, wc = (wv & 1) * 64;
    const int li = lane & 15, g = lane >> 4;
    const int lr8 = lane >> 3, lc8 = lane & 7;

    f32x4 acc[4][4];
#pragma unroll
    for (int i = 0; i < 4; ++i)
#pragma unroll
        for (int j = 0; j < 4; ++j) acc[i][j] = (f32x4)0.0f;

    for (int k0 = 0; k0 < 1024; k0 += 64) {
        __syncthreads();
#pragma unroll
        for (int ld = 0; ld < 4; ++ld) {
            int r0 = wv * 32 + ld * 8;
            gload_lds16(ob + (size_t)(rb + r0 + lr8) * 1024 + k0 + lc8 * 8, As + r0 * 128);
            gload_lds16(wob + (size_t)(cb + r0 + lr8) * 1024 + k0 + lc8 * 8, Bs + r0 * 128);
        }
        __syncthreads();
#pragma unroll
        for (int ks = 0; ks < 2; ++ks) {
            bf16x8 af[4], bfr[4];
#pragma unroll
            for (int m = 0; m < 4; ++m)
                af[m] = *(const bf16x8*)(As + (wr + m * 16 + li) * 128 + ks * 64 + g * 16);
#pragma unroll
            for (int n = 0; n < 4; ++n)
                bfr[n] = *(const bf16x8*)(Bs + (wc + n * 16 + li) * 128 + ks * 64 + g * 16);
#pragma unroll
            for (int m = 0; m < 4; ++m)
#pragma unroll
                for (int n = 0; n < 4; ++n)
                    acc[m][n] = __builtin_amdgcn_mfma_f32_16x16x32_bf16(af[m], bfr[n], acc[m][n], 0, 0, 0);
        }
    }
#pragma unroll
    for (int m = 0; m < 4; ++m) {
        int t = rb + wr + m * 16 + g * 4;
#pragma unroll
        for (int r = 0; r < 4; ++r) {
#pragma unroll
            for (int n = 0; n < 4; ++n) {
                int col = cb + wc + n * 16 + li;
                out[(size_t)(t + r) * 1024 + col] = acc[m][n][r];
            }
        }
    }
}

// ---------------------------------------------------------------------------
extern "C" void kernel_launch(void* const* d_in, const int* in_sizes, int n_in,
                              void* d_out, int out_size, void* d_ws, size_t ws_size,
                              hipStream_t stream)
{
    const float* x     = (const float*)d_in[0];
    const float* Wq    = (const float*)d_in[1];
    const float* Wk    = (const float*)d_in[2];
    const float* Wv    = (const float*)d_in[3];
    const float* Wlr   = (const float*)d_in[4];
    const float* Wbeta = (const float*)d_in[5];
    const float* Wo    = (const float*)d_in[6];
    const float* Wi0   = (const float*)d_in[7];
    const float* Wo0   = (const float*)d_in[8];
    float* out = (float*)d_out;

    char* od = (char*)d_out;
    u16* xb  = (u16*)(od);                 // dead before out_proj overwrites
    u16* wb  = (u16*)(od + 33554432u);
    u16* wlb = (u16*)(od + 39845888u);

    char* ws = (char*)d_ws;
    u16* qb        = (u16*)(ws);
    u16* kb        = (u16*)(ws + 33554432u);
    u16* vb        = (u16*)(ws + 67108864u);
    u16* obuf      = (u16*)(ws + 100663296u);
    float* lrc_all = (float*)(ws + 134217728u);
    u16* wob       = (u16*)(ws + 134283264u);
    if (ws_size < 136380416u) return;

    convert_kernel<<<2048, 256, 0, stream>>>(x, Wq, Wk, Wv, Wo, Wlr, Wbeta,
                                             xb, wb, wob, wlb);
    proj_qkv_kernel<<<dim3(24, 128), 256, 0, stream>>>(xb, wb, qb, kb, vb);
    lrwd_kernel<<<128, 256, 0, stream>>>(xb, wlb, lrc_all);
    scan_kernel<<<64, 256, 0, stream>>>(qb, kb, vb, lrc_all, Wi0, Wo0, obuf);
    out_proj_kernel<<<dim3(8, 128), 256, 0, stream>>>(obuf, wob, out);
}

// Round 5
// 607.827 us; speedup vs baseline: 1.1263x; 1.1263x over previous
//
#include <hip/hip_runtime.h>
#include <stdint.h>

typedef unsigned short u16;
typedef uint32_t u32;
typedef __attribute__((ext_vector_type(4))) float f32x4;
typedef __attribute__((ext_vector_type(8))) short bf16x8;

#define DEVINL __device__ __forceinline__

DEVINL u16 f2bf(float f) {
    union { float f; u32 u; } a; a.f = f;
    u32 u = a.u;
    return (u16)((u + 0x7fffu + ((u >> 16) & 1u)) >> 16);   // RNE
}
DEVINL u32 pk2(float a, float b) { return (u32)f2bf(a) | ((u32)f2bf(b) << 16); }

// 128B-row swizzled tile (conflict-free vector row reads) — R2/R4-verified
DEVINL u32 swz128(u32 row, u32 colb) { return row * 128u + (colb ^ ((row & 7u) << 4)); }

// async global->LDS, 16B per lane
DEVINL void gload_lds16(const u16* g, char* l) {
    __builtin_amdgcn_global_load_lds(
        (const __attribute__((address_space(1))) void*)g,
        (__attribute__((address_space(3))) void*)l, 16, 0, 0);
}

// 4x4 transpose among 4 lanes (lane&3) over the 4 regs of v (R4-verified):
// result: (lane q, reg r) holds original (lane r, reg q).
DEVINL f32x4 trans4(f32x4 v, int q) {
    float s0 = __shfl_xor(v[0], 1), s1 = __shfl_xor(v[1], 1),
          s2 = __shfl_xor(v[2], 1), s3 = __shfl_xor(v[3], 1);
    f32x4 t;
    bool q1 = (q & 1) != 0;
    t[0] = q1 ? s1 : v[0];
    t[1] = q1 ? v[1] : s0;
    t[2] = q1 ? s3 : v[2];
    t[3] = q1 ? v[3] : s2;
    float u0 = __shfl_xor(t[0], 2), u1 = __shfl_xor(t[1], 2),
          u2 = __shfl_xor(t[2], 2), u3 = __shfl_xor(t[3], 2);
    f32x4 r;
    bool q2 = (q & 2) != 0;
    r[0] = q2 ? u2 : t[0];
    r[1] = q2 ? u3 : t[1];
    r[2] = q2 ? t[2] : u0;
    r[3] = q2 ? t[3] : u1;
    return r;
}

// ---------------------------------------------------------------------------
// Kernel 0: fp32 -> bf16 convert pass
// ---------------------------------------------------------------------------
__global__ __launch_bounds__(256) void convert_kernel(
    const float* __restrict__ x, const float* __restrict__ Wq,
    const float* __restrict__ Wk, const float* __restrict__ Wv,
    const float* __restrict__ Wo, const float* __restrict__ Wlr,
    const float* __restrict__ Wbeta,
    u16* __restrict__ xb, u16* __restrict__ wb, u16* __restrict__ wob,
    u16* __restrict__ wlb)
{
    const int t0 = blockIdx.x * 256 + threadIdx.x;
    const int stride = gridDim.x * 256;
    auto cv = [&](const float* src, u16* dst, int n4) {
        for (int i = t0; i < n4; i += stride) {
            float4 v = ((const float4*)src)[i];
            uint2 p;
            p.x = pk2(v.x, v.y);
            p.y = pk2(v.z, v.w);
            ((uint2*)dst)[i] = p;
        }
    };
    cv(x, xb, 4194304);
    cv(Wq, wb, 262144);
    cv(Wk, wb + 1048576, 262144);
    cv(Wv, wb + 2097152, 262144);
    cv(Wo, wob, 262144);
    cv(Wlr, wlb, 8192);
    cv(Wbeta, wlb + 32768, 8192);
}

// ---------------------------------------------------------------------------
// Kernel A: q/k/v projections (bf16 in, bf16 out, fused silu for q,k)
// ---------------------------------------------------------------------------
__global__ __launch_bounds__(256) void proj_qkv_kernel(
    const u16* __restrict__ xb, const u16* __restrict__ wb,
    u16* __restrict__ qb, u16* __restrict__ kb, u16* __restrict__ vb)
{
    __shared__ __align__(16) char As[128 * 128];
    __shared__ __align__(16) char Bs[128 * 128];
    const int bn = blockIdx.x;
    const int bm = blockIdx.y;
    const int wsel = bn >> 3;
    u16* __restrict__ dst = (wsel == 0) ? qb : ((wsel == 1) ? kb : vb);
    const int cb = (bn & 7) * 128;
    const int wrow = bn * 128;
    const int rb = bm * 128;
    const int tid = threadIdx.x;
    const int lane = tid & 63;
    const int wv = tid >> 6;
    const int wr = (wv >> 1) * 64, wc = (wv & 1) * 64;
    const int li = lane & 15, g = lane >> 4;
    const int lr8 = lane >> 3, lc8 = lane & 7;

    f32x4 acc[4][4];
#pragma unroll
    for (int i = 0; i < 4; ++i)
#pragma unroll
        for (int j = 0; j < 4; ++j) acc[i][j] = (f32x4)0.0f;

    for (int k0 = 0; k0 < 1024; k0 += 64) {
        __syncthreads();
#pragma unroll
        for (int ld = 0; ld < 4; ++ld) {
            int r0 = wv * 32 + ld * 8;
            gload_lds16(xb + (size_t)(rb + r0 + lr8) * 1024 + k0 + lc8 * 8, As + r0 * 128);
            gload_lds16(wb + (size_t)(wrow + r0 + lr8) * 1024 + k0 + lc8 * 8, Bs + r0 * 128);
        }
        __syncthreads();
#pragma unroll
        for (int ks = 0; ks < 2; ++ks) {
            bf16x8 af[4], bfr[4];
#pragma unroll
            for (int m = 0; m < 4; ++m)
                af[m] = *(const bf16x8*)(As + (wr + m * 16 + li) * 128 + ks * 64 + g * 16);
#pragma unroll
            for (int n = 0; n < 4; ++n)
                bfr[n] = *(const bf16x8*)(Bs + (wc + n * 16 + li) * 128 + ks * 64 + g * 16);
#pragma unroll
            for (int m = 0; m < 4; ++m)
#pragma unroll
                for (int n = 0; n < 4; ++n)
                    acc[m][n] = __builtin_amdgcn_mfma_f32_16x16x32_bf16(af[m], bfr[n], acc[m][n], 0, 0, 0);
        }
    }
    const bool do_silu = (wsel < 2);
#pragma unroll
    for (int m = 0; m < 4; ++m) {
        int t = rb + wr + m * 16 + g * 4;
#pragma unroll
        for (int r = 0; r < 4; ++r) {
#pragma unroll
            for (int n = 0; n < 4; ++n) {
                float v = acc[m][n][r];
                if (do_silu) v = v / (1.0f + __expf(-v));
                int col = cb + wc + n * 16 + li;
                dst[(size_t)(t + r) * 1024 + col] = f2bf(v);
            }
        }
    }
}

// ---------------------------------------------------------------------------
// Kernel B: lr/wd heads as MFMA GEMM + on-chip per-chunk mean
// ---------------------------------------------------------------------------
__global__ __launch_bounds__(256) void lrwd_kernel(
    const u16* __restrict__ xb, const u16* __restrict__ wlb,
    float* __restrict__ lrc_all)
{
    __shared__ __align__(16) char As[128 * 128];
    __shared__ __align__(16) char Bs[64 * 128];
    __shared__ float red[128][65];
    const int bm = blockIdx.x;
    const int rb = bm * 128;
    const int tid = threadIdx.x;
    const int lane = tid & 63;
    const int wv = tid >> 6;
    const int li = lane & 15, g = lane >> 4;
    const int lr8 = lane >> 3, lc8 = lane & 7;

    f32x4 acc[2][4];
#pragma unroll
    for (int i = 0; i < 2; ++i)
#pragma unroll
        for (int j = 0; j < 4; ++j) acc[i][j] = (f32x4)0.0f;

    for (int k0 = 0; k0 < 1024; k0 += 64) {
        __syncthreads();
#pragma unroll
        for (int ld = 0; ld < 4; ++ld) {
            int r0 = wv * 32 + ld * 8;
            gload_lds16(xb + (size_t)(rb + r0 + lr8) * 1024 + k0 + lc8 * 8, As + r0 * 128);
        }
#pragma unroll
        for (int ld = 0; ld < 2; ++ld) {
            int r0 = wv * 16 + ld * 8;
            gload_lds16(wlb + (size_t)(r0 + lr8) * 1024 + k0 + lc8 * 8, Bs + r0 * 128);
        }
        __syncthreads();
#pragma unroll
        for (int ks = 0; ks < 2; ++ks) {
            bf16x8 af[2], bfr[4];
#pragma unroll
            for (int m = 0; m < 2; ++m)
                af[m] = *(const bf16x8*)(As + (wv * 32 + m * 16 + li) * 128 + ks * 64 + g * 16);
#pragma unroll
            for (int n = 0; n < 4; ++n)
                bfr[n] = *(const bf16x8*)(Bs + (n * 16 + li) * 128 + ks * 64 + g * 16);
#pragma unroll
            for (int m = 0; m < 2; ++m)
#pragma unroll
                for (int n = 0; n < 4; ++n)
                    acc[m][n] = __builtin_amdgcn_mfma_f32_16x16x32_bf16(af[m], bfr[n], acc[m][n], 0, 0, 0);
        }
    }
#pragma unroll
    for (int m = 0; m < 2; ++m) {
#pragma unroll
        for (int n = 0; n < 4; ++n) {
            int col = n * 16 + li;
            float scale = (col < 32) ? 1e-3f : 0.9f;
#pragma unroll
            for (int r = 0; r < 4; ++r) {
                int t = wv * 32 + m * 16 + g * 4 + r;
                float s = acc[m][n][r];
                red[t][col] = scale / (1.0f + __expf(-s));
            }
        }
    }
    __syncthreads();
    if (tid < 128) {
        int chunk = tid >> 6, col = tid & 63;
        float s = 0.f;
#pragma unroll
        for (int i = 0; i < 64; ++i) s += red[chunk * 64 + i][col];
        int b = bm >> 5;
        int cidx = (bm & 31) * 2 + chunk;
        lrc_all[((size_t)(b * 64 + cidx)) * 64 + col] = s * (1.0f / 64.0f);
    }
}

// ---------------------------------------------------------------------------
// Kernel C: chunk scan, 8 waves / 512 threads, dual task pipelines.
//   Waves 0-3 (A): M1 -> softmax -> SPQ; M3 -> o store; q/k/v staging.
//   Waves 4-7 (B): M2 -> softmax -> M4' -> spart -> SPTN -> M5;
//                  gz -> SGZN -> M6; state update (fp32 regs).
// 2 barriers/chunk.  All fragment mappings identical to R4-verified kernel.
// ---------------------------------------------------------------------------
__global__ __launch_bounds__(512) void scan_kernel(
    const u16* __restrict__ qb, const u16* __restrict__ kb, const u16* __restrict__ vb,
    const float* __restrict__ lrc_all, const float* __restrict__ Wi0,
    const float* __restrict__ Wo0, u16* __restrict__ ob)
{
    const int bh = blockIdx.x;
    const int b = bh >> 4, h = bh & 15;
    const int tid = threadIdx.x;
    const int lane = tid & 63;
    const int w8 = tid >> 6;            // 0..7
    const bool isA = (w8 < 4);
    const int wq = w8;                  // A-wave index (0..3) when isA
    const int wk = w8 - 4;              // B-wave index (0..3) when !isA
    const int li = lane & 15, g = lane >> 4;
    const int q4 = li & 3, b4 = li & 12;

    // double-buffered chunk tiles
    __shared__ __align__(16) char SQ2[2][8192];    // q   [n][d]
    __shared__ __align__(16) char Kc2[2][8192];    // k   [n][d]
    __shared__ __align__(16) char Vc2[2][8192];    // v   [n][d]
    __shared__ __align__(16) char KcT2[2][8192];   // k^T [d][n]
    __shared__ __align__(16) char VcT2[2][8192];   // v^T [d][n]
    __shared__ __align__(16) char SWoT2[2][8192];  // Wo^T[d][D] (dbuf: M3 reads cur)
    // single-buffered
    __shared__ __align__(16) char SWiN[8192];      // Wi  [D][d]
    __shared__ __align__(16) char SWoN[8192];      // Wo  [D][d]
    __shared__ __align__(16) char SPQ[8192];       // pq  [n][D]
    __shared__ __align__(16) char SPTN[8192];      // p^T [D][n]
    __shared__ __align__(16) char SGZN[8192];      // gz^T[D][n]
    __shared__ float spart[256];
    __shared__ float lrc[256];

    // ---- B-side state: fp32 regs (MFMA C-layout) + LDS mirrors ----
    f32x4 WiR[4], WoR[4];
    if (!isA) {
#pragma unroll
        for (int tn = 0; tn < 4; ++tn) {
            int d = tn * 16 + li;
#pragma unroll
            for (int r = 0; r < 4; ++r) {
                int D = wk * 16 + g * 4 + r;
                WiR[tn][r] = Wi0[((size_t)D * 16 + h) * 64 + d];
                WoR[tn][r] = Wo0[((size_t)D * 16 + h) * 64 + d];
            }
            *(uint2*)(SWoT2[0] + swz128(d, wk * 32 + g * 8)) =
                make_uint2(pk2(WoR[tn][0], WoR[tn][1]), pk2(WoR[tn][2], WoR[tn][3]));
            f32x4 ti = trans4(WiR[tn], q4);
            *(uint2*)(SWiN + swz128(wk * 16 + g * 4 + q4, tn * 32 + b4 * 2)) =
                make_uint2(pk2(ti[0], ti[1]), pk2(ti[2], ti[3]));
            f32x4 to = trans4(WoR[tn], q4);
            *(uint2*)(SWoN + swz128(wk * 16 + g * 4 + q4, tn * 32 + b4 * 2)) =
                make_uint2(pk2(to[0], to[1]), pk2(to[2], to[3]));
        }
    }
    if (tid < 256) {
        int cc = tid >> 2, j = tid & 3;
        lrc[cc * 4 + j] = lrc_all[((size_t)(b * 64 + cc)) * 64 + j * 16 + h];
    }

    // ---- A-side staging (identical math to R4 commit, 256 A-threads) ----
    const int nb4 = ((tid & 255) >> 4) * 4;
    const int db4 = (tid & 15) * 4;
    uint4 pq_[2];
    uint2 pk_[4], pv_[4];
    auto prefetch = [&](int c) {
        const size_t base = ((size_t)(b * 4096 + c * 64)) * 1024 + h * 64;
#pragma unroll
        for (int p = 0; p < 2; ++p) {
            int id = p * 256 + (tid & 255);
            int n = id >> 3;
            int d0 = (id & 7) * 8;
            pq_[p] = *(const uint4*)(qb + base + (size_t)n * 1024 + d0);
        }
#pragma unroll
        for (int j = 0; j < 4; ++j) {
            pk_[j] = *(const uint2*)(kb + base + (size_t)(nb4 + j) * 1024 + db4);
            pv_[j] = *(const uint2*)(vb + base + (size_t)(nb4 + j) * 1024 + db4);
        }
    };
    auto commit = [&](int buf) {
#pragma unroll
        for (int p = 0; p < 2; ++p) {
            int id = p * 256 + (tid & 255);
            int n = id >> 3;
            int d0 = (id & 7) * 8;
            *(uint4*)(SQ2[buf] + swz128(n, d0 * 2)) = pq_[p];
        }
#pragma unroll
        for (int j = 0; j < 4; ++j) {
            *(uint2*)(Kc2[buf] + swz128(nb4 + j, db4 * 2)) = pk_[j];
            *(uint2*)(Vc2[buf] + swz128(nb4 + j, db4 * 2)) = pv_[j];
        }
#pragma unroll
        for (int i = 0; i < 4; ++i) {
            u32 k0 = (((i & 2) ? pk_[0].y : pk_[0].x) >> ((i & 1) * 16)) & 0xffffu;
            u32 k1 = (((i & 2) ? pk_[1].y : pk_[1].x) >> ((i & 1) * 16)) & 0xffffu;
            u32 k2 = (((i & 2) ? pk_[2].y : pk_[2].x) >> ((i & 1) * 16)) & 0xffffu;
            u32 k3 = (((i & 2) ? pk_[3].y : pk_[3].x) >> ((i & 1) * 16)) & 0xffffu;
            *(uint2*)(KcT2[buf] + swz128(db4 + i, nb4 * 2)) =
                make_uint2(k0 | (k1 << 16), k2 | (k3 << 16));
            u32 v0 = (((i & 2) ? pv_[0].y : pv_[0].x) >> ((i & 1) * 16)) & 0xffffu;
            u32 v1 = (((i & 2) ? pv_[1].y : pv_[1].x) >> ((i & 1) * 16)) & 0xffffu;
            u32 v2 = (((i & 2) ? pv_[2].y : pv_[2].x) >> ((i & 1) * 16)) & 0xffffu;
            u32 v3 = (((i & 2) ? pv_[3].y : pv_[3].x) >> ((i & 1) * 16)) & 0xffffu;
            *(uint2*)(VcT2[buf] + swz128(db4 + i, nb4 * 2)) =
                make_uint2(v0 | (v1 << 16), v2 | (v3 << 16));
        }
    };

    if (isA) { prefetch(0); commit(0); }
    __syncthreads();

    for (int c = 0; c < 64; ++c) {
        const int cur = c & 1, nxt = cur ^ 1;
        f32x4 pk[4], aT[4], go[4];          // B-side live values

        if (isA) {
            // ================= A pipeline: M1 + softmax + SPQ =================
            if (c + 1 < 64) prefetch(c + 1);
            bf16x8 wiA0 = *(const bf16x8*)(SWiN + swz128(wq * 16 + li, g * 16));
            bf16x8 wiA1 = *(const bf16x8*)(SWiN + swz128(wq * 16 + li, 64 + g * 16));
            f32x4 sq[4];
#pragma unroll
            for (int tn = 0; tn < 4; ++tn) {
                bf16x8 b0 = *(const bf16x8*)(SQ2[cur] + swz128(tn * 16 + li, g * 16));
                bf16x8 b1 = *(const bf16x8*)(SQ2[cur] + swz128(tn * 16 + li, 64 + g * 16));
                f32x4 z = (f32x4)0.0f;
                z = __builtin_amdgcn_mfma_f32_16x16x32_bf16(wiA0, b0, z, 0, 0, 0);
                z = __builtin_amdgcn_mfma_f32_16x16x32_bf16(wiA1, b1, z, 0, 0, 0);
                sq[tn] = z;
            }
#pragma unroll
            for (int r = 0; r < 4; ++r) {
                float m = fmaxf(fmaxf(sq[0][r], sq[1][r]), fmaxf(sq[2][r], sq[3][r]));
                m = fmaxf(m, __shfl_xor(m, 1)); m = fmaxf(m, __shfl_xor(m, 2));
                m = fmaxf(m, __shfl_xor(m, 4)); m = fmaxf(m, __shfl_xor(m, 8));
                float e0 = __expf(sq[0][r] - m), e1 = __expf(sq[1][r] - m);
                float e2 = __expf(sq[2][r] - m), e3 = __expf(sq[3][r] - m);
                float s = e0 + e1 + e2 + e3;
                s += __shfl_xor(s, 1); s += __shfl_xor(s, 2);
                s += __shfl_xor(s, 4); s += __shfl_xor(s, 8);
                float inv = 1.0f / s;
                sq[0][r] = e0 * inv; sq[1][r] = e1 * inv; sq[2][r] = e2 * inv; sq[3][r] = e3 * inv;
            }
#pragma unroll
            for (int tn = 0; tn < 4; ++tn) {
                int n = tn * 16 + li;
                *(uint2*)(SPQ + swz128(n, (wq * 16 + g * 4) * 2)) =
                    make_uint2(pk2(sq[tn][0], sq[tn][1]), pk2(sq[tn][2], sq[tn][3]));
            }
        } else {
            // ============== B pipeline: M2 + softmax + M4' + spart + SPTN + M5 ==============
            bf16x8 wiA0 = *(const bf16x8*)(SWiN + swz128(wk * 16 + li, g * 16));
            bf16x8 wiA1 = *(const bf16x8*)(SWiN + swz128(wk * 16 + li, 64 + g * 16));
            __builtin_amdgcn_s_setprio(1);
#pragma unroll
            for (int tn = 0; tn < 4; ++tn) {
                bf16x8 b0 = *(const bf16x8*)(Kc2[cur] + swz128(tn * 16 + li, g * 16));
                bf16x8 b1 = *(const bf16x8*)(Kc2[cur] + swz128(tn * 16 + li, 64 + g * 16));
                f32x4 z = (f32x4)0.0f;
                z = __builtin_amdgcn_mfma_f32_16x16x32_bf16(wiA0, b0, z, 0, 0, 0);
                z = __builtin_amdgcn_mfma_f32_16x16x32_bf16(wiA1, b1, z, 0, 0, 0);
                pk[tn] = z;
            }
            __builtin_amdgcn_s_setprio(0);
#pragma unroll
            for (int r = 0; r < 4; ++r) {
                float m = fmaxf(fmaxf(pk[0][r], pk[1][r]), fmaxf(pk[2][r], pk[3][r]));
                m = fmaxf(m, __shfl_xor(m, 1)); m = fmaxf(m, __shfl_xor(m, 2));
                m = fmaxf(m, __shfl_xor(m, 4)); m = fmaxf(m, __shfl_xor(m, 8));
                float e0 = __expf(pk[0][r] - m), e1 = __expf(pk[1][r] - m);
                float e2 = __expf(pk[2][r] - m), e3 = __expf(pk[3][r] - m);
                float s = e0 + e1 + e2 + e3;
                s += __shfl_xor(s, 1); s += __shfl_xor(s, 2);
                s += __shfl_xor(s, 4); s += __shfl_xor(s, 8);
                float inv = 1.0f / s;
                pk[0][r] = e0 * inv; pk[1][r] = e1 * inv; pk[2][r] = e2 * inv; pk[3][r] = e3 * inv;
            }
            bf16x8 woA0 = *(const bf16x8*)(SWoN + swz128(wk * 16 + li, g * 16));
            bf16x8 woA1 = *(const bf16x8*)(SWoN + swz128(wk * 16 + li, 64 + g * 16));
            __builtin_amdgcn_s_setprio(1);
#pragma unroll
            for (int tn = 0; tn < 4; ++tn) {
                bf16x8 b0 = *(const bf16x8*)(Vc2[cur] + swz128(tn * 16 + li, g * 16));
                bf16x8 b1 = *(const bf16x8*)(Vc2[cur] + swz128(tn * 16 + li, 64 + g * 16));
                f32x4 z = (f32x4)0.0f;
                z = __builtin_amdgcn_mfma_f32_16x16x32_bf16(woA0, b0, z, 0, 0, 0);
                z = __builtin_amdgcn_mfma_f32_16x16x32_bf16(woA1, b1, z, 0, 0, 0);
                aT[tn] = z;
            }
            __builtin_amdgcn_s_setprio(0);
#pragma unroll
            for (int tn = 0; tn < 4; ++tn) {
                f32x4 t4 = pk[tn] * aT[tn];
                float s_ = t4[0] + t4[1] + t4[2] + t4[3];
                s_ += __shfl_xor(s_, 16);
                s_ += __shfl_xor(s_, 32);
                if (g == 0) spart[wk * 64 + tn * 16 + li] = s_;
            }
            // SPTN (wave-local rows) then M5 immediately (go)
#pragma unroll
            for (int tn = 0; tn < 4; ++tn) {
                f32x4 tp = trans4(pk[tn], q4);
                *(uint2*)(SPTN + swz128(wk * 16 + g * 4 + q4, tn * 32 + b4 * 2)) =
                    make_uint2(pk2(tp[0], tp[1]), pk2(tp[2], tp[3]));
            }
            {
                bf16x8 a0 = *(const bf16x8*)(SPTN + swz128(wk * 16 + li, g * 16));
                bf16x8 a1 = *(const bf16x8*)(SPTN + swz128(wk * 16 + li, 64 + g * 16));
                __builtin_amdgcn_s_setprio(1);
#pragma unroll
                for (int tn = 0; tn < 4; ++tn) {
                    bf16x8 b0 = *(const bf16x8*)(VcT2[cur] + swz128(tn * 16 + li, g * 16));
                    bf16x8 b1 = *(const bf16x8*)(VcT2[cur] + swz128(tn * 16 + li, 64 + g * 16));
                    f32x4 z = (f32x4)0.0f;
                    z = __builtin_amdgcn_mfma_f32_16x16x32_bf16(a0, b0, z, 0, 0, 0);
                    z = __builtin_amdgcn_mfma_f32_16x16x32_bf16(a1, b1, z, 0, 0, 0);
                    go[tn] = z;
                }
                __builtin_amdgcn_s_setprio(0);
            }
        }
        __syncthreads();   // B1: spart + SPQ visible

        if (isA) {
            // ================= A: M3 + o store + commit(c+1) =================
            bf16x8 a0 = *(const bf16x8*)(SPQ + swz128(wq * 16 + li, g * 16));
            bf16x8 a1 = *(const bf16x8*)(SPQ + swz128(wq * 16 + li, 64 + g * 16));
            f32x4 o4[4];
#pragma unroll
            for (int tn = 0; tn < 4; ++tn) {
                bf16x8 b0 = *(const bf16x8*)(SWoT2[cur] + swz128(tn * 16 + li, g * 16));
                bf16x8 b1 = *(const bf16x8*)(SWoT2[cur] + swz128(tn * 16 + li, 64 + g * 16));
                f32x4 z = (f32x4)0.0f;
                z = __builtin_amdgcn_mfma_f32_16x16x32_bf16(a0, b0, z, 0, 0, 0);
                z = __builtin_amdgcn_mfma_f32_16x16x32_bf16(a1, b1, z, 0, 0, 0);
                o4[tn] = z;
            }
            const size_t obase = ((size_t)(b * 4096 + c * 64)) * 1024 + h * 64;
            const int n_ = wq * 16 + g * 4 + q4;
#pragma unroll
            for (int tn = 0; tn < 4; ++tn) {
                f32x4 to = trans4(o4[tn], q4);
                *(uint2*)(ob + obase + (size_t)n_ * 1024 + tn * 16 + b4) =
                    make_uint2(pk2(to[0], to[1]), pk2(to[2], to[3]));
            }
            if (c + 1 < 64) commit(nxt);
        } else {
            // ================= B: gz + SGZN + M6 + state update =================
            f32x4 gz[4];
#pragma unroll
            for (int tn = 0; tn < 4; ++tn) {
                int n = tn * 16 + li;
                float sn = spart[n] + spart[64 + n] + spart[128 + n] + spart[192 + n];
#pragma unroll
                for (int r = 0; r < 4; ++r) gz[tn][r] = pk[tn][r] * (sn - aT[tn][r]);
                f32x4 tg = trans4(gz[tn], q4);
                *(uint2*)(SGZN + swz128(wk * 16 + g * 4 + q4, tn * 32 + b4 * 2)) =
                    make_uint2(pk2(tg[0], tg[1]), pk2(tg[2], tg[3]));
            }
            f32x4 gi[4];
            {
                bf16x8 a0 = *(const bf16x8*)(SGZN + swz128(wk * 16 + li, g * 16));
                bf16x8 a1 = *(const bf16x8*)(SGZN + swz128(wk * 16 + li, 64 + g * 16));
                __builtin_amdgcn_s_setprio(1);
#pragma unroll
                for (int tn = 0; tn < 4; ++tn) {
                    bf16x8 b0 = *(const bf16x8*)(KcT2[cur] + swz128(tn * 16 + li, g * 16));
                    bf16x8 b1 = *(const bf16x8*)(KcT2[cur] + swz128(tn * 16 + li, 64 + g * 16));
                    f32x4 z = (f32x4)0.0f;
                    z = __builtin_amdgcn_mfma_f32_16x16x32_bf16(a0, b0, z, 0, 0, 0);
                    z = __builtin_amdgcn_mfma_f32_16x16x32_bf16(a1, b1, z, 0, 0, 0);
                    gi[tn] = z;
                }
                __builtin_amdgcn_s_setprio(0);
            }
            if (c + 1 < 64) {
                float lin = lrc[c * 4 + 0], lout = lrc[c * 4 + 1];
                float win = lrc[c * 4 + 2], wout = lrc[c * 4 + 3];
#pragma unroll
                for (int tn = 0; tn < 4; ++tn) {
                    WiR[tn] = win * WiR[tn] - lin * gi[tn];
                    WoR[tn] = wout * WoR[tn] + lout * go[tn];   // grad_out = -go
                    int d = tn * 16 + li;
                    *(uint2*)(SWoT2[nxt] + swz128(d, wk * 32 + g * 8)) =
                        make_uint2(pk2(WoR[tn][0], WoR[tn][1]), pk2(WoR[tn][2], WoR[tn][3]));
                    f32x4 ti = trans4(WiR[tn], q4);
                    *(uint2*)(SWiN + swz128(wk * 16 + g * 4 + q4, tn * 32 + b4 * 2)) =
                        make_uint2(pk2(ti[0], ti[1]), pk2(ti[2], ti[3]));
                    f32x4 to = trans4(WoR[tn], q4);
                    *(uint2*)(SWoN + swz128(wk * 16 + g * 4 + q4, tn * 32 + b4 * 2)) =
                        make_uint2(pk2(to[0], to[1]), pk2(to[2], to[3]));
                }
            }
        }
        __syncthreads();   // Bend: tiles(c+1) + state(c+1) visible
    }
}

// ---------------------------------------------------------------------------
// Kernel D: out[t][m] = sum_j o[t][j] * Wo[m][j]
// ---------------------------------------------------------------------------
__global__ __launch_bounds__(256) void out_proj_kernel(
    const u16* __restrict__ ob, const u16* __restrict__ wob, float* __restrict__ out)
{
    __shared__ __align__(16) char As[128 * 128];
    __shared__ __align__(16) char Bs[128 * 128];
    const int bn = blockIdx.x;
    const int bm = blockIdx.y;
    const int cb = bn * 128;
    const int rb = bm * 128;
    const int tid = threadIdx.x;
    const int lane = tid & 63;
    const int wv = tid >> 6;
    const int wr = (wv >> 1) * 64, wc = (wv & 1) * 64;
    const int li = lane & 15, g = lane >> 4;
    const int lr8 = lane >> 3, lc8 = lane & 7;

    f32x4 acc[4][4];
#pragma unroll
    for (int i = 0; i < 4; ++i)
#pragma unroll
        for (int j = 0; j < 4; ++j) acc[i][j] = (f32x4)0.0f;

    for (int k0 = 0; k0 < 1024; k0 += 64) {
        __syncthreads();
#pragma unroll
        for (int ld = 0; ld < 4; ++ld) {
            int r0 = wv * 32 + ld * 8;
            gload_lds16(ob + (size_t)(rb + r0 + lr8) * 1024 + k0 + lc8 * 8, As + r0 * 128);
            gload_lds16(wob + (size_t)(cb + r0 + lr8) * 1024 + k0 + lc8 * 8, Bs + r0 * 128);
        }
        __syncthreads();
#pragma unroll
        for (int ks = 0; ks < 2; ++ks) {
            bf16x8 af[4], bfr[4];
#pragma unroll
            for (int m = 0; m < 4; ++m)
                af[m] = *(const bf16x8*)(As + (wr + m * 16 + li) * 128 + ks * 64 + g * 16);
#pragma unroll
            for (int n = 0; n < 4; ++n)
                bfr[n] = *(const bf16x8*)(Bs + (wc + n * 16 + li) * 128 + ks * 64 + g * 16);
#pragma unroll
            for (int m = 0; m < 4; ++m)
#pragma unroll
                for (int n = 0; n < 4; ++n)
                    acc[m][n] = __builtin_amdgcn_mfma_f32_16x16x32_bf16(af[m], bfr[n], acc[m][n], 0, 0, 0);
        }
    }
#pragma unroll
    for (int m = 0; m < 4; ++m) {
        int t = rb + wr + m * 16 + g * 4;
#pragma unroll
        for (int r = 0; r < 4; ++r) {
#pragma unroll
            for (int n = 0; n < 4; ++n) {
                int col = cb + wc + n * 16 + li;
                out[(size_t)(t + r) * 1024 + col] = acc[m][n][r];
            }
        }
    }
}

// ---------------------------------------------------------------------------
extern "C" void kernel_launch(void* const* d_in, const int* in_sizes, int n_in,
                              void* d_out, int out_size, void* d_ws, size_t ws_size,
                              hipStream_t stream)
{
    const float* x     = (const float*)d_in[0];
    const float* Wq    = (const float*)d_in[1];
    const float* Wk    = (const float*)d_in[2];
    const float* Wv    = (const float*)d_in[3];
    const float* Wlr   = (const float*)d_in[4];
    const float* Wbeta = (const float*)d_in[5];
    const float* Wo    = (const float*)d_in[6];
    const float* Wi0   = (const float*)d_in[7];
    const float* Wo0   = (const float*)d_in[8];
    float* out = (float*)d_out;

    char* od = (char*)d_out;
    u16* xb  = (u16*)(od);                 // dead before out_proj overwrites
    u16* wb  = (u16*)(od + 33554432u);
    u16* wlb = (u16*)(od + 39845888u);

    char* ws = (char*)d_ws;
    u16* qb        = (u16*)(ws);
    u16* kb        = (u16*)(ws + 33554432u);
    u16* vb        = (u16*)(ws + 67108864u);
    u16* obuf      = (u16*)(ws + 100663296u);
    float* lrc_all = (float*)(ws + 134217728u);
    u16* wob       = (u16*)(ws + 134283264u);
    if (ws_size < 136380416u) return;

    convert_kernel<<<2048, 256, 0, stream>>>(x, Wq, Wk, Wv, Wo, Wlr, Wbeta,
                                             xb, wb, wob, wlb);
    proj_qkv_kernel<<<dim3(24, 128), 256, 0, stream>>>(xb, wb, qb, kb, vb);
    lrwd_kernel<<<128, 256, 0, stream>>>(xb, wlb, lrc_all);
    scan_kernel<<<64, 512, 0, stream>>>(qb, kb, vb, lrc_all, Wi0, Wo0, obuf);
    out_proj_kernel<<<dim3(8, 128), 256, 0, stream>>>(obuf, wob, out);
}